// Round 9
// baseline (103.521 us; speedup 1.0000x reference)
//
#include <hip/hip_runtime.h>

// out[b,o] = sum_k w[idx[b],o,k] * x[b,k];  B=2048, C=64, IN=OUT=512.
//
// r15: r14 (stages-before-scan) -0.6us. Two FIFO artifacts remain:
//  (1) scan data-wait sits AFTER the stages in the vmcnt FIFO -> 64KB must
//      land before the compare; gathers + T0 then run on an EMPTY pipe.
//      Fix: idx loads FIRST (oldest), stages second, vmcnt(16)="idx landed,
//      stages flying". Scan/list are LDS-only (lgkm) -> barrier_lgkm
//      completes the list WITHOUT draining stages. Gathers issue behind
//      the stages; cvt waits ride the same busy stream. Prologue = one
//      continuous HBM burst.
//  (2) stage(t+2) issued after the whole chunk+kreduce leaves each tile's
//      MFMA+reduce (~1us) HBM-idle. After wf ds_reads + lgkm barrier, Wb
//      is dead (W held in regs on fast path) -> issue stage(t+2) THERE.
//      vm8 at T1-end still guarantees stage(2) landed (oldest-first drain;
//      may eat <=2 store-slots of stage3 -- harmless). Slow path (n>64,
//      P~1e-8) keeps late issue.
// Also: ng0>2 (n>32) is ~45% probable, not rare -- fast path now gathers
// all <=4 groups uniformly (safe: gathers are FIFO-behind the stages).
// Rest = r14: grid 512 (2 blocks/CU), 128KB W stream/block, source-side
// 16B-granule XOR swizzle, XCD-bijective swizzle, K-split + lgkm-only
// 2-round kreduce, counted vm8/vm0 boundaries, deterministic stores.

constexpr int Bsz  = 2048;
constexpr int Ccnt = 64;
constexpr int INF  = 512;
constexpr int OUTF = 512;
constexpr int THREADS = 256;   // 4 waves = 4 K-quarters
constexpr int OT  = 16;        // out rows per staged tile
constexpr int TPB = 4;         // consecutive tiles per block
constexpr int NBUF = 2;        // staging depth
constexpr int NBLK = Ccnt * (OUTF / (OT * TPB));   // 512

typedef __attribute__((ext_vector_type(8))) short bf16x8;
typedef __attribute__((ext_vector_type(4))) float f32x4;

#if __has_builtin(__builtin_amdgcn_cvt_pk_bf16_f32)
typedef __attribute__((ext_vector_type(2))) __bf16 bf16x2_t;
__device__ __forceinline__ int cvt2i(float a, float b) {
    union { bf16x2_t v; int i; } u;
    u.v = __builtin_amdgcn_cvt_pk_bf16_f32(a, b);
    return u.i;
}
#else
__device__ __forceinline__ unsigned f2bf(float f) {
    union { float f; unsigned u; } v; v.f = f;
    return (v.u + 0x7FFFu + ((v.u >> 16) & 1u)) >> 16;   // RNE
}
__device__ __forceinline__ int cvt2i(float a, float b) {
    return (int)(f2bf(a) | (f2bf(b) << 16));
}
#endif

__device__ __forceinline__ bf16x8 cvt8(float4 a, float4 b) {
    union { bf16x8 v; int i[4]; } u;
    u.i[0] = cvt2i(a.x, a.y);
    u.i[1] = cvt2i(a.z, a.w);
    u.i[2] = cvt2i(b.x, b.y);
    u.i[3] = cvt2i(b.z, b.w);
    return u.v;
}

// async 16B/lane global -> LDS (dest = wave-uniform base + lane*16)
__device__ __forceinline__ void gld_lds16(const float* g, float* l) {
    __builtin_amdgcn_global_load_lds(
        (const __attribute__((address_space(1))) float*)g,
        (__attribute__((address_space(3))) float*)l, 16, 0, 0);
}

// workgroup barrier that does NOT touch vmcnt (keeps staging in flight)
__device__ __forceinline__ void barrier_lgkm() {
    asm volatile("s_waitcnt lgkmcnt(0)" ::: "memory");
    __builtin_amdgcn_s_barrier();
    asm volatile("" ::: "memory");
}

// counted-vmcnt barriers: oldest ops landed, newest keep flying
__device__ __forceinline__ void vm8_barrier() {
    asm volatile("s_waitcnt vmcnt(8)" ::: "memory");
    __builtin_amdgcn_sched_barrier(0);
    __builtin_amdgcn_s_barrier();
    asm volatile("" ::: "memory");
}
__device__ __forceinline__ void vm0_barrier() {
    asm volatile("s_waitcnt vmcnt(0)" ::: "memory");
    __builtin_amdgcn_sched_barrier(0);
    __builtin_amdgcn_s_barrier();
    asm volatile("" ::: "memory");
}

// stage one 16x512 f32 tile (contiguous 32KB) into LDS, 8 x 1KB insts/wave.
// Element (r,k) lands at dst[r*512 + (((k>>2) ^ (r&7)))*4 + (k&3)] (16B-
// granule XOR swizzle applied on the SOURCE side within 128B lines ->
// coalescing identical to a linear copy; reads de-swizzle with same XOR).
__device__ __forceinline__ void stage_tile(const float* wt, float* dst,
                                           int wave, int lane) {
#pragma unroll
    for (int i = 0; i < 8; ++i) {
        const int inst = wave * 8 + i;
        const int r = inst >> 1;
        const int h = inst & 1;
        const int p = r & 7;
        const float* src = wt + (size_t)r * INF + (h * 64 + (lane ^ p)) * 4;
        gld_lds16(src, dst + inst * 256);
    }
}

// cross-wave K-reduce + store, rounds of 2 groups (fixed order ->
// deterministic). lgkm-only barriers: never drains in-flight staging.
__device__ __forceinline__ void kreduce_store(
        const f32x4* acc, int ng, int s0, int n, int o0,
        int wave, int lane, int mrow, int quad,
        const unsigned short* list, float (*red)[3][4][64],
        float* __restrict__ out) {
#pragma unroll
    for (int r0 = 0; r0 < 4; r0 += 2) {
        if (r0 < ng) {                       // uniform across block
            if (wave != 0) {
#pragma unroll
                for (int g = 0; g < 2; ++g) {
                    if (r0 + g < ng) {
#pragma unroll
                        for (int j = 0; j < 4; ++j)
                            red[g][wave - 1][j][lane] = acc[r0 + g][j];
                    }
                }
            }
            barrier_lgkm();
            if (wave == 0) {
#pragma unroll
                for (int g = 0; g < 2; ++g) {
                    if (r0 + g < ng) {
                        const int s = s0 + (r0 + g) * 16 + mrow;
                        if (s < n) {
                            f32x4 a = acc[r0 + g];
#pragma unroll
                            for (int wv2 = 0; wv2 < 3; ++wv2)
#pragma unroll
                                for (int j = 0; j < 4; ++j)
                                    a[j] += red[g][wv2][j][lane];
                            float* dst = out + (size_t)list[s] * OUTF
                                             + o0 + quad * 4;
                            *(float4*)dst = make_float4(a[0], a[1], a[2], a[3]);
                        }
                    }
                }
            }
            barrier_lgkm();                  // red reusable next round
        }
    }
}

__global__ __launch_bounds__(THREADS, 2)
void switching_linear_kernel(const float* __restrict__ x,
                             const int* __restrict__ idx,
                             const float* __restrict__ w,
                             float* __restrict__ out) {
    __shared__ float Wl[NBUF][OT * INF];    // 64 KB double-buffered W tile
    __shared__ unsigned short list[Bsz];    // 4 KB
    __shared__ int ls_n;
    __shared__ float red[2][3][4][64];      // 6 KB (rounds of 2 groups)

    const int tid  = threadIdx.x;
    const int wave = tid >> 6;
    const int lane = tid & 63;

    // XCD-bijective swizzle: the 8 blocks of a class land on one XCD
    const int bid   = ((int)blockIdx.x & 7) * (NBLK / 8) + ((int)blockIdx.x >> 3);
    const int c     = bid >> 3;                 // class
    const int obase = (bid & 7) * (OT * TPB);   // first of 64 contiguous rows

    if (tid == 0) ls_n = 0;
    __syncthreads();   // nothing in flight yet

    const float* wc = w + (size_t)c * OUTF * INF + (size_t)obase * INF;

    // ---- idx loads FIRST (oldest in FIFO), then the W stream ----
    const int4* idx4 = (const int4*)idx;
    int4 ia = idx4[tid * 2];
    int4 ib = idx4[tid * 2 + 1];
    __builtin_amdgcn_sched_barrier(0);   // pin: idx loads precede stages

    stage_tile(wc,                    Wl[0], wave, lane);   // stage(0)
    stage_tile(wc + (size_t)OT * INF, Wl[1], wave, lane);   // stage(1)

    asm volatile("s_waitcnt vmcnt(16)" ::: "memory");  // idx landed;
    __builtin_amdgcn_sched_barrier(0);                 // stages flying

    // ---- scan + list build: LDS-only (lgkm) -> stages keep flying ----
    int my[8] = {ia.x, ia.y, ia.z, ia.w, ib.x, ib.y, ib.z, ib.w};
#pragma unroll
    for (int i = 0; i < 8; ++i)
        if (my[i] == c) list[atomicAdd(&ls_n, 1)] = (unsigned short)(tid * 8 + i);

    barrier_lgkm();   // list complete block-wide; stages STILL in flight
    const int n = ls_n;
    if (n == 0) {     // uniform; drain in-flight stages and exit
        asm volatile("s_waitcnt vmcnt(0)" ::: "memory");
        return;
    }

    const int mrow = lane & 15;   // A row / C col
    const int quad = lane >> 4;   // k segment / C row group
    const int k0   = wave * (INF / 4);
    const int p    = mrow & 7;

    const int ng0 = (n >= 64) ? 4 : ((n + 15) >> 4);

    // ---- x gathers (FIFO-behind the stages: their waits ride the same
    //      busy stream) + cvt; covers all <=4 groups (n<=64) ----
    bf16x8 xf[4][4];
#pragma unroll
    for (int g = 0; g < 4; ++g) {
        if (g < ng0) {
            const int s  = g * 16 + mrow;
            const int sc = s < n ? s : n - 1;
            const float* bp = x + (size_t)list[sc] * INF + k0 + quad * 8;
#pragma unroll
            for (int i = 0; i < 4; ++i) {
                float4 b0 = *(const float4*)(bp + i * 32);
                float4 b1 = *(const float4*)(bp + i * 32 + 4);
                xf[g][i] = cvt8(b0, b1);
            }
        }
    }

    vm0_barrier();   // everything landed; Wl[0], Wl[1] valid block-wide

    const bool fast = (n <= 64);   // uniform

    for (int ot = 0; ot < TPB; ++ot) {
        const float* Wb = Wl[ot & 1];
        const int o0 = obase + ot * OT;

        // A-fragments for this tile (LDS -> regs, lgkm domain only)
        bf16x8 wf[4];
#pragma unroll
        for (int t = 0; t < 4; ++t) {
            const int gb = (k0 >> 2) + t * 8 + quad * 2;   // granule in row
            float4 a0 = *(const float4*)&Wb[mrow * INF + ((gb)     ^ p) * 4];
            float4 a1 = *(const float4*)&Wb[mrow * INF + ((gb + 1) ^ p) * 4];
            wf[t] = cvt8(a0, a1);
        }

        // All waves done reading Wb -> safe to overwrite. Issue stage(ot+2)
        // EARLY so this tile's MFMA+reduce overlaps its flight (fast path:
        // W lives in wf regs; nothing re-reads Wb).
        barrier_lgkm();
        if (fast && ot + 2 < TPB)
            stage_tile(wc + (size_t)((ot + 2) * OT) * INF, Wl[ot & 1],
                       wave, lane);

        // ---- chunk 0: pure register MFMA (no vmem) ----
        {
            f32x4 acc[4];
#pragma unroll
            for (int g = 0; g < 4; ++g) acc[g] = (f32x4){0.f, 0.f, 0.f, 0.f};
#pragma unroll
            for (int g = 0; g < 4; ++g) {
                if (g < ng0) {
#pragma unroll
                    for (int i = 0; i < 4; ++i)
                        acc[g] = __builtin_amdgcn_mfma_f32_16x16x32_bf16(
                                     wf[i], xf[g][i], acc[g], 0, 0, 0);
                }
            }
            kreduce_store(acc, ng0, 0, n, o0, wave, lane, mrow, quad,
                          list, red, out);
        }

        if (!fast) {
            // ---- very rare slow path (n>64): in-loop gathers, re-reads Wb;
            //      stage late (after kreduce's final barrier) ----
            for (int s0 = 64; s0 < n; s0 += 64) {
                const int rem = n - s0;
                const int ng  = rem >= 64 ? 4 : (rem + 15) >> 4;

                f32x4 acc[4];
#pragma unroll
                for (int g = 0; g < 4; ++g) acc[g] = (f32x4){0.f, 0.f, 0.f, 0.f};
#pragma unroll
                for (int g = 0; g < 4; ++g) {
                    if (g < ng) {
                        const int s  = s0 + g * 16 + mrow;
                        const int sc = s < n ? s : n - 1;
                        const float* bp = x + (size_t)list[sc] * INF + k0 + quad * 8;
#pragma unroll
                        for (int i = 0; i < 4; ++i) {
                            float4 b0 = *(const float4*)(bp + i * 32);
                            float4 b1 = *(const float4*)(bp + i * 32 + 4);
                            acc[g] = __builtin_amdgcn_mfma_f32_16x16x32_bf16(
                                         wf[i], cvt8(b0, b1), acc[g], 0, 0, 0);
                        }
                    }
                }
                kreduce_store(acc, ng, s0, n, o0, wave, lane, mrow, quad,
                              list, red, out);
            }
            if (ot + 2 < TPB)
                stage_tile(wc + (size_t)((ot + 2) * OT) * INF, Wl[ot & 1],
                           wave, lane);
        }

        // Boundaries: ot=0 -> none (Wl[1] landed since prologue);
        // ot=1 -> vm8 (stage2+older stores drained, stage3 keeps flying);
        // ot=2 -> vm0 (stage3 landed).
        if (ot == 1)      vm8_barrier();
        else if (ot == 2) vm0_barrier();
    }
}

extern "C" void kernel_launch(void* const* d_in, const int* in_sizes, int n_in,
                              void* d_out, int out_size, void* d_ws, size_t ws_size,
                              hipStream_t stream) {
    const float* x   = (const float*)d_in[0];
    const int*   idx = (const int*)d_in[1];
    const float* w   = (const float*)d_in[2];
    float* out = (float*)d_out;

    switching_linear_kernel<<<dim3(NBLK), dim3(THREADS), 0, stream>>>(x, idx, w, out);
}

// Round 10
// 101.682 us; speedup vs baseline: 1.0181x; 1.0181x over previous
//
#include <hip/hip_runtime.h>

// out[b,o] = sum_k w[idx[b],o,k] * x[b,k];  B=2048, C=64, IN=OUT=512.
//
// r16 == r14 REVERT (best measured: 101.9us). r15's fine-grained overlap
// (idx-first scan-on-lgkm + early stage(t+2) issue) regressed +1.6us:
// the extra per-tile read-fence barrier + FIFO reordering cost more than
// the overlap gained -- 2-blocks/CU TLP already covers intra-block gaps
// (same lesson as r12/r13). Session ladder: r6 ~29us kernel -> r9
// vmem-consumer-free tile loop (~19) -> r10 counted vmcnt (neutral) ->
// r11 gathers-first prologue (~17.5) -> r14 stages-before-scan (~17).
// Kernel ~17us vs ~11.5us mandatory-traffic floor (W 64MB read once +
// x/idx/out ~8.5MB at 6.3TB/s); residual = 512 per-block prologues +
// tail drain, shown unrecoverable by r12/r13/r15.
//
// Design: grid 512 = 64 classes x 8 row-groups (2 blocks/CU); block owns
// 4 consecutive 16-row tiles = contiguous 128KB W stream, double-buffered
// 2x32KB with source-side 16B-granule XOR swizzle (conflict-free
// ds_read_b128, coalescing = linear copy); stages issued BEFORE idx scan
// (scan's data-wait keeps HBM busy; list __syncthreads doubles as "Wl
// valid"); x gathered once into regs (bf16 cvt); K split across 4 waves;
// 2-round lgkm-only kreduce (never drains stages); counted vm8/vm0 tile
// boundaries; XCD-bijective block swizzle; deterministic (fixed-order
// reduce, each out element written once).

constexpr int Bsz  = 2048;
constexpr int Ccnt = 64;
constexpr int INF  = 512;
constexpr int OUTF = 512;
constexpr int THREADS = 256;   // 4 waves = 4 K-quarters
constexpr int OT  = 16;        // out rows per staged tile
constexpr int TPB = 4;         // consecutive tiles per block
constexpr int NBUF = 2;        // staging depth
constexpr int NBLK = Ccnt * (OUTF / (OT * TPB));   // 512

typedef __attribute__((ext_vector_type(8))) short bf16x8;
typedef __attribute__((ext_vector_type(4))) float f32x4;

#if __has_builtin(__builtin_amdgcn_cvt_pk_bf16_f32)
typedef __attribute__((ext_vector_type(2))) __bf16 bf16x2_t;
__device__ __forceinline__ int cvt2i(float a, float b) {
    union { bf16x2_t v; int i; } u;
    u.v = __builtin_amdgcn_cvt_pk_bf16_f32(a, b);
    return u.i;
}
#else
__device__ __forceinline__ unsigned f2bf(float f) {
    union { float f; unsigned u; } v; v.f = f;
    return (v.u + 0x7FFFu + ((v.u >> 16) & 1u)) >> 16;   // RNE
}
__device__ __forceinline__ int cvt2i(float a, float b) {
    return (int)(f2bf(a) | (f2bf(b) << 16));
}
#endif

__device__ __forceinline__ bf16x8 cvt8(float4 a, float4 b) {
    union { bf16x8 v; int i[4]; } u;
    u.i[0] = cvt2i(a.x, a.y);
    u.i[1] = cvt2i(a.z, a.w);
    u.i[2] = cvt2i(b.x, b.y);
    u.i[3] = cvt2i(b.z, b.w);
    return u.v;
}

// async 16B/lane global -> LDS (dest = wave-uniform base + lane*16)
__device__ __forceinline__ void gld_lds16(const float* g, float* l) {
    __builtin_amdgcn_global_load_lds(
        (const __attribute__((address_space(1))) float*)g,
        (__attribute__((address_space(3))) float*)l, 16, 0, 0);
}

// workgroup barrier that does NOT touch vmcnt (keeps staging in flight)
__device__ __forceinline__ void barrier_lgkm() {
    asm volatile("s_waitcnt lgkmcnt(0)" ::: "memory");
    __builtin_amdgcn_s_barrier();
    asm volatile("" ::: "memory");
}

// counted-vmcnt barriers: oldest ops landed, newest 8 keep flying
__device__ __forceinline__ void vm8_barrier() {
    asm volatile("s_waitcnt vmcnt(8)" ::: "memory");
    __builtin_amdgcn_sched_barrier(0);
    __builtin_amdgcn_s_barrier();
    asm volatile("" ::: "memory");
}
__device__ __forceinline__ void vm0_barrier() {
    asm volatile("s_waitcnt vmcnt(0)" ::: "memory");
    __builtin_amdgcn_sched_barrier(0);
    __builtin_amdgcn_s_barrier();
    asm volatile("" ::: "memory");
}

// stage one 16x512 f32 tile (contiguous 32KB) into LDS, 8 x 1KB insts/wave.
// Element (r,k) lands at dst[r*512 + (((k>>2) ^ (r&7)))*4 + (k&3)] (16B-
// granule XOR swizzle applied on the SOURCE side within 128B lines ->
// coalescing identical to a linear copy; reads de-swizzle with same XOR).
__device__ __forceinline__ void stage_tile(const float* wt, float* dst,
                                           int wave, int lane) {
#pragma unroll
    for (int i = 0; i < 8; ++i) {
        const int inst = wave * 8 + i;
        const int r = inst >> 1;
        const int h = inst & 1;
        const int p = r & 7;
        const float* src = wt + (size_t)r * INF + (h * 64 + (lane ^ p)) * 4;
        gld_lds16(src, dst + inst * 256);
    }
}

// cross-wave K-reduce + store, rounds of 2 groups (fixed order ->
// deterministic). lgkm-only barriers: never drains in-flight staging.
__device__ __forceinline__ void kreduce_store(
        const f32x4* acc, int ng, int s0, int n, int o0,
        int wave, int lane, int mrow, int quad,
        const unsigned short* list, float (*red)[3][4][64],
        float* __restrict__ out) {
#pragma unroll
    for (int r0 = 0; r0 < 4; r0 += 2) {
        if (r0 < ng) {                       // uniform across block
            if (wave != 0) {
#pragma unroll
                for (int g = 0; g < 2; ++g) {
                    if (r0 + g < ng) {
#pragma unroll
                        for (int j = 0; j < 4; ++j)
                            red[g][wave - 1][j][lane] = acc[r0 + g][j];
                    }
                }
            }
            barrier_lgkm();
            if (wave == 0) {
#pragma unroll
                for (int g = 0; g < 2; ++g) {
                    if (r0 + g < ng) {
                        const int s = s0 + (r0 + g) * 16 + mrow;
                        if (s < n) {
                            f32x4 a = acc[r0 + g];
#pragma unroll
                            for (int wv2 = 0; wv2 < 3; ++wv2)
#pragma unroll
                                for (int j = 0; j < 4; ++j)
                                    a[j] += red[g][wv2][j][lane];
                            float* dst = out + (size_t)list[s] * OUTF
                                             + o0 + quad * 4;
                            *(float4*)dst = make_float4(a[0], a[1], a[2], a[3]);
                        }
                    }
                }
            }
            barrier_lgkm();                  // red reusable next round
        }
    }
}

__global__ __launch_bounds__(THREADS, 2)
void switching_linear_kernel(const float* __restrict__ x,
                             const int* __restrict__ idx,
                             const float* __restrict__ w,
                             float* __restrict__ out) {
    __shared__ float Wl[NBUF][OT * INF];    // 64 KB double-buffered W tile
    __shared__ unsigned short list[Bsz];    // 4 KB
    __shared__ int ls_n;
    __shared__ float red[2][3][4][64];      // 6 KB (rounds of 2 groups)

    const int tid  = threadIdx.x;
    const int wave = tid >> 6;
    const int lane = tid & 63;

    // XCD-bijective swizzle: the 8 blocks of a class land on one XCD
    const int bid   = ((int)blockIdx.x & 7) * (NBLK / 8) + ((int)blockIdx.x >> 3);
    const int c     = bid >> 3;                 // class
    const int obase = (bid & 7) * (OT * TPB);   // first of 64 contiguous rows

    if (tid == 0) ls_n = 0;
    __syncthreads();   // nothing in flight yet

    const float* wc = w + (size_t)c * OUTF * INF + (size_t)obase * INF;

    // ---- W stream starts at t~0: stages need no list ----
    stage_tile(wc,                    Wl[0], wave, lane);   // stage(0)
    stage_tile(wc + (size_t)OT * INF, Wl[1], wave, lane);   // stage(1)
    __builtin_amdgcn_sched_barrier(0);   // pin: stages precede idx loads

    // ---- idx scan (2 x int4) + list build; HBM busy with stages ----
    const int4* idx4 = (const int4*)idx;
    int4 ia = idx4[tid * 2];
    int4 ib = idx4[tid * 2 + 1];
    int my[8] = {ia.x, ia.y, ia.z, ia.w, ib.x, ib.y, ib.z, ib.w};
#pragma unroll
    for (int i = 0; i < 8; ++i)
        if (my[i] == c) list[atomicAdd(&ls_n, 1)] = (unsigned short)(tid * 8 + i);

    // my[] data-wait (FIFO) drained this wave's stage ops; barrier makes
    // Wl[0], Wl[1] valid block-wide AND list complete.
    __syncthreads();
    const int n = ls_n;
    if (n == 0) {   // uniform; drain any straggler state and exit
        asm volatile("s_waitcnt vmcnt(0)" ::: "memory");
        return;
    }

    const int mrow = lane & 15;   // A row / C col
    const int quad = lane >> 4;   // k segment / C row group
    const int k0   = wave * (INF / 4);
    const int p    = mrow & 7;

    const int ng0 = (n >= 64) ? 4 : ((n + 15) >> 4);
    const int ngp = ng0 < 2 ? ng0 : 2;   // common-case groups (n<=32)

    // ---- x gathers + cvt (nothing in flight; plain loads) ----
    bf16x8 xf[4][4];                // chunk-0 x fragments, reused by all tiles
#pragma unroll
    for (int g = 0; g < 2; ++g) {
        if (g < ngp) {
            const int s  = g * 16 + mrow;
            const int sc = s < n ? s : n - 1;
            const float* bp = x + (size_t)list[sc] * INF + k0 + quad * 8;
#pragma unroll
            for (int i = 0; i < 4; ++i) {
                float4 b0 = *(const float4*)(bp + i * 32);
                float4 b1 = *(const float4*)(bp + i * 32 + 4);
                xf[g][i] = cvt8(b0, b1);
            }
        }
    }
    if (ng0 > 2) {   // n>32
#pragma unroll
        for (int g = 2; g < 4; ++g) {
            if (g < ng0) {
                const int s  = g * 16 + mrow;
                const int sc = s < n ? s : n - 1;
                const float* bp = x + (size_t)list[sc] * INF + k0 + quad * 8;
#pragma unroll
                for (int i = 0; i < 4; ++i) {
                    float4 b0 = *(const float4*)(bp + i * 32);
                    float4 b1 = *(const float4*)(bp + i * 32 + 4);
                    xf[g][i] = cvt8(b0, b1);
                }
            }
        }
    }

    for (int ot = 0; ot < TPB; ++ot) {
        const float* Wb = Wl[ot & 1];
        const int o0 = obase + ot * OT;

        // A-fragments for this tile (LDS -> regs, lgkm domain only)
        bf16x8 wf[4];
#pragma unroll
        for (int t = 0; t < 4; ++t) {
            const int gb = (k0 >> 2) + t * 8 + quad * 2;   // granule in row
            float4 a0 = *(const float4*)&Wb[mrow * INF + ((gb)     ^ p) * 4];
            float4 a1 = *(const float4*)&Wb[mrow * INF + ((gb + 1) ^ p) * 4];
            wf[t] = cvt8(a0, a1);
        }

        // ---- chunk 0: pure register MFMA (no vmem -> stages keep flying)
        {
            f32x4 acc[4];
#pragma unroll
            for (int g = 0; g < 4; ++g) acc[g] = (f32x4){0.f, 0.f, 0.f, 0.f};
#pragma unroll
            for (int g = 0; g < 4; ++g) {
                if (g < ng0) {
#pragma unroll
                    for (int i = 0; i < 4; ++i)
                        acc[g] = __builtin_amdgcn_mfma_f32_16x16x32_bf16(
                                     wf[i], xf[g][i], acc[g], 0, 0, 0);
                }
            }
            kreduce_store(acc, ng0, 0, n, o0, wave, lane, mrow, quad,
                          list, red, out);
        }

        // ---- rare slow path: chunks beyond 64 samples (gathers in-loop) ----
        for (int s0 = 64; s0 < n; s0 += 64) {
            const int rem = n - s0;
            const int ng  = rem >= 64 ? 4 : (rem + 15) >> 4;

            f32x4 acc[4];
#pragma unroll
            for (int g = 0; g < 4; ++g) acc[g] = (f32x4){0.f, 0.f, 0.f, 0.f};
#pragma unroll
            for (int g = 0; g < 4; ++g) {
                if (g < ng) {
                    const int s  = s0 + g * 16 + mrow;
                    const int sc = s < n ? s : n - 1;
                    const float* bp = x + (size_t)list[sc] * INF + k0 + quad * 8;
#pragma unroll
                    for (int i = 0; i < 4; ++i) {
                        float4 b0 = *(const float4*)(bp + i * 32);
                        float4 b1 = *(const float4*)(bp + i * 32 + 4);
                        acc[g] = __builtin_amdgcn_mfma_f32_16x16x32_bf16(
                                     wf[i], cvt8(b0, b1), acc[g], 0, 0, 0);
                    }
                }
            }
            kreduce_store(acc, ng, s0, n, o0, wave, lane, mrow, quad,
                          list, red, out);
        }

        // kreduce's final barrier => all waves done reading Wb; B[ot&1] free.
        // Stores precede the stage in FIFO -> counted waits stay EXACT.
        if (ot + 2 < TPB)
            stage_tile(wc + (size_t)((ot + 2) * OT) * INF, Wl[ot & 1],
                       wave, lane);

        // Boundaries: ot=0 -> none (Wl[1] landed since prologue);
        // ot=1 -> vm8 (stores+stage2 done, stage3 flying); ot=2 -> vm0.
        if (ot == 1)      vm8_barrier();
        else if (ot == 2) vm0_barrier();
    }
}

extern "C" void kernel_launch(void* const* d_in, const int* in_sizes, int n_in,
                              void* d_out, int out_size, void* d_ws, size_t ws_size,
                              hipStream_t stream) {
    const float* x   = (const float*)d_in[0];
    const int*   idx = (const int*)d_in[1];
    const float* w   = (const float*)d_in[2];
    float* out = (float*)d_out;

    switching_linear_kernel<<<dim3(NBLK), dim3(THREADS), 0, stream>>>(x, idx, w, out);
}